// Round 1
// baseline (93.243 us; speedup 1.0000x reference)
//
#include <hip/hip_runtime.h>
#include <hip/hip_bf16.h>

typedef __bf16 bf16x8 __attribute__((ext_vector_type(8)));
typedef __bf16 bf16x4 __attribute__((ext_vector_type(4)));
typedef float  f32x16 __attribute__((ext_vector_type(16)));
typedef float  f32x4  __attribute__((ext_vector_type(4)));

#define HD     2048   // H*D floats per token row
#define DH     128    // head dim
#define KVB    32     // kv chunk
#define NCHUNK 64     // 2048/32
#define VSTR   36     // padded stride for V^T tile (odd word stride/2 -> 2-way max, free)

// grid 256 = 16 qblk x 16 heads, 256 threads = 4 warps x 32 q-rows each.
__global__ __launch_bounds__(256, 1)
void fmha_fwd(const float* __restrict__ Qg, const float* __restrict__ Kg,
              const float* __restrict__ Vg, float* __restrict__ Og)
{
    __shared__ __align__(16) __bf16 klds[2][32 * 128];     // K chunk, swizzled rows
    __shared__ __align__(16) __bf16 vtlds[2][DH * VSTR];   // V^T chunk [dv][kv]

    const int tid  = threadIdx.x;
    const int lane = tid & 63;
    const int wrp  = tid >> 6;
    const int g    = lane >> 5;   // half-wave
    const int l31  = lane & 31;

    // XCD-aware mapping: blocks b, b+8, b+16... share head -> per-head K/V stays in one XCD's L2
    const int b    = blockIdx.x;
    const int h    = 2 * (b & 7) + ((b >> 3) >> 4);
    const int qblk = (b >> 3) & 15;

    const float qscale = 1.4426950408889634f * 0.08838834764831845f; // log2(e)/sqrt(128)

    const int q = qblk * 128 + wrp * 32 + l31;

    // ---- Q fragments in registers (B-operand of QK^T): lane=q-row, elem e -> d = db*16+8g+e
    bf16x8 qf[8];
    {
        const float* qrow = Qg + (size_t)q * HD + h * DH;
        #pragma unroll
        for (int db = 0; db < 8; ++db) {
            f32x4 a = *(const f32x4*)(qrow + db * 16 + 8 * g);
            f32x4 c = *(const f32x4*)(qrow + db * 16 + 8 * g + 4);
            bf16x8 f;
            f[0] = (__bf16)(a[0] * qscale); f[1] = (__bf16)(a[1] * qscale);
            f[2] = (__bf16)(a[2] * qscale); f[3] = (__bf16)(a[3] * qscale);
            f[4] = (__bf16)(c[0] * qscale); f[5] = (__bf16)(c[1] * qscale);
            f[6] = (__bf16)(c[2] * qscale); f[7] = (__bf16)(c[3] * qscale);
            qf[db] = f;
        }
    }

    // ---- staging work split (256 threads)
    const int krow = tid >> 3, kc = tid & 7;          // K: 32 rows x 8 chunkers
    const int vkv  = tid & 31, vdv0 = (tid >> 5) * 16; // V: 32 kv x 8 dv-slices
    const float* kbase = Kg + (size_t)h * DH;
    const float* vbase = Vg + (size_t)h * DH;

    f32x4 kreg0, kreg1, kreg2, kreg3, vreg0, vreg1, vreg2, vreg3;

    auto stage_load = [&](int t) {   // issue global loads only (T14 issue-early)
        const float* kp = kbase + (size_t)(t * KVB + krow) * HD + kc * 8;
        kreg0 = *(const f32x4*)(kp);
        kreg1 = *(const f32x4*)(kp + 4);
        kreg2 = *(const f32x4*)(kp + 64);
        kreg3 = *(const f32x4*)(kp + 68);
        const float* vp = vbase + (size_t)(t * KVB + vkv) * HD + vdv0;
        vreg0 = *(const f32x4*)(vp);
        vreg1 = *(const f32x4*)(vp + 4);
        vreg2 = *(const f32x4*)(vp + 8);
        vreg3 = *(const f32x4*)(vp + 12);
    };

    auto stage_write = [&](int buf) {  // cvt + LDS write (write-late)
        bf16x8 k0, k1;
        k0[0]=(__bf16)kreg0[0]; k0[1]=(__bf16)kreg0[1]; k0[2]=(__bf16)kreg0[2]; k0[3]=(__bf16)kreg0[3];
        k0[4]=(__bf16)kreg1[0]; k0[5]=(__bf16)kreg1[1]; k0[6]=(__bf16)kreg1[2]; k0[7]=(__bf16)kreg1[3];
        k1[0]=(__bf16)kreg2[0]; k1[1]=(__bf16)kreg2[1]; k1[2]=(__bf16)kreg2[2]; k1[3]=(__bf16)kreg2[3];
        k1[4]=(__bf16)kreg3[0]; k1[5]=(__bf16)kreg3[1]; k1[6]=(__bf16)kreg3[2]; k1[7]=(__bf16)kreg3[3];
        const int swz = (krow & 7) << 3;   // element-units; == byte ^ ((row&7)<<4)
        *(bf16x8*)&klds[buf][krow * 128 + ((kc * 8) ^ swz)]      = k0;
        *(bf16x8*)&klds[buf][krow * 128 + ((kc * 8 + 64) ^ swz)] = k1;
        #pragma unroll
        for (int jj = 0; jj < 4; ++jj) {
            f32x4 vv = (jj == 0) ? vreg0 : (jj == 1) ? vreg1 : (jj == 2) ? vreg2 : vreg3;
            #pragma unroll
            for (int e = 0; e < 4; ++e)
                vtlds[buf][(vdv0 + jj * 4 + e) * VSTR + vkv] = (__bf16)vv[e];
        }
    };

    float mrun = -1e30f, lrun = 0.0f;
    f32x16 o0, o1, o2, o3;
    #pragma unroll
    for (int r = 0; r < 16; ++r) { o0[r] = 0.f; o1[r] = 0.f; o2[r] = 0.f; o3[r] = 0.f; }

    stage_load(0);
    stage_write(0);

    #pragma unroll 2
    for (int t = 0; t < NCHUNK; ++t) {
        const int cur = t & 1;
        if (t + 1 < NCHUNK) stage_load(t + 1);
        __syncthreads();  // buf[cur] writes visible; everyone done reading buf[cur^1]

        // ---- QK^T (swapped): S^T[kv][q], two independent acc chains over d
        f32x16 sa, sb;
        #pragma unroll
        for (int r = 0; r < 16; ++r) { sa[r] = 0.f; sb[r] = 0.f; }
        const int kswz = (l31 & 7) << 3;
        #pragma unroll
        for (int db = 0; db < 4; ++db) {
            bf16x8 kfa = *(const bf16x8*)&klds[cur][l31 * 128 + (((2*db)   * 16 + g * 8) ^ kswz)];
            sa = __builtin_amdgcn_mfma_f32_32x32x16_bf16(kfa, qf[2*db],   sa, 0, 0, 0);
            bf16x8 kfb = *(const bf16x8*)&klds[cur][l31 * 128 + (((2*db+1) * 16 + g * 8) ^ kswz)];
            sb = __builtin_amdgcn_mfma_f32_32x32x16_bf16(kfb, qf[2*db+1], sb, 0, 0, 0);
        }
        f32x16 s;
        #pragma unroll
        for (int r = 0; r < 16; ++r) s[r] = sa[r] + sb[r];

        // ---- online softmax (lane owns 16 of 32 kv for q-row l31; partner is lane^32)
        float m8[8];
        #pragma unroll
        for (int r = 0; r < 8; ++r) m8[r] = fmaxf(s[r], s[r + 8]);
        float tmax = fmaxf(fmaxf(fmaxf(m8[0], m8[4]), fmaxf(m8[1], m8[5])),
                           fmaxf(fmaxf(m8[2], m8[6]), fmaxf(m8[3], m8[7])));
        tmax = fmaxf(tmax, __shfl_xor(tmax, 32, 64));
        const float mnew  = fmaxf(mrun, tmax);
        const float alpha = __builtin_amdgcn_exp2f(mrun - mnew);

        float p[16];
        #pragma unroll
        for (int r = 0; r < 16; ++r) p[r] = __builtin_amdgcn_exp2f(s[r] - mnew);
        float ps0 = 0, ps1 = 0, ps2 = 0, ps3 = 0;
        #pragma unroll
        for (int r = 0; r < 4; ++r) { ps0 += p[r]; ps1 += p[r+4]; ps2 += p[r+8]; ps3 += p[r+12]; }
        lrun = lrun * alpha + ((ps0 + ps1) + (ps2 + ps3));
        mrun = mnew;

        #pragma unroll
        for (int r = 0; r < 16; ++r) { o0[r] *= alpha; o1[r] *= alpha; o2[r] *= alpha; o3[r] *= alpha; }

        // P -> bf16 fragments; S^T C/D reg order == PV B-operand slot order (same k bijection)
        bf16x8 pf0, pf1;
        #pragma unroll
        for (int e = 0; e < 8; ++e) { pf0[e] = (__bf16)p[e]; pf1[e] = (__bf16)p[8 + e]; }

        // ---- PV: O^T[dv][q] += V^T[dv][kv] * P^T[kv][q], 4 dv-blocks x 2 kv-halves
        #pragma unroll
        for (int bb = 0; bb < 4; ++bb) {
            const __bf16* vb = &vtlds[cur][(bb * 32 + l31) * VSTR];
            bf16x4 a0 = *(const bf16x4*)(vb + 4 * g);
            bf16x4 a1 = *(const bf16x4*)(vb + 8 + 4 * g);
            bf16x8 va;
            va[0]=a0[0]; va[1]=a0[1]; va[2]=a0[2]; va[3]=a0[3];
            va[4]=a1[0]; va[5]=a1[1]; va[6]=a1[2]; va[7]=a1[3];
            f32x16& oo = (bb == 0) ? o0 : (bb == 1) ? o1 : (bb == 2) ? o2 : o3;
            oo = __builtin_amdgcn_mfma_f32_32x32x16_bf16(va, pf0, oo, 0, 0, 0);
            bf16x4 b0 = *(const bf16x4*)(vb + 16 + 4 * g);
            bf16x4 b1 = *(const bf16x4*)(vb + 24 + 4 * g);
            va[0]=b0[0]; va[1]=b0[1]; va[2]=b0[2]; va[3]=b0[3];
            va[4]=b1[0]; va[5]=b1[1]; va[6]=b1[2]; va[7]=b1[3];
            oo = __builtin_amdgcn_mfma_f32_32x32x16_bf16(va, pf1, oo, 0, 0, 0);
        }

        if (t + 1 < NCHUNK) stage_write(cur ^ 1);
    }

    // ---- epilogue: combine partner-half row sums, normalize, store O (row q, contiguous dv runs)
    const float ltot = lrun + __shfl_xor(lrun, 32, 64);
    const float inv  = 1.0f / ltot;
    float* orow = Og + (size_t)q * HD + h * DH;
    #pragma unroll
    for (int bb = 0; bb < 4; ++bb) {
        const f32x16& oo = (bb == 0) ? o0 : (bb == 1) ? o1 : (bb == 2) ? o2 : o3;
        #pragma unroll
        for (int jj = 0; jj < 4; ++jj) {
            f32x4 v;
            v[0] = oo[4*jj+0] * inv; v[1] = oo[4*jj+1] * inv;
            v[2] = oo[4*jj+2] * inv; v[3] = oo[4*jj+3] * inv;
            *(f32x4*)(orow + bb * 32 + 8 * jj + 4 * g) = v;
        }
    }
}

extern "C" void kernel_launch(void* const* d_in, const int* in_sizes, int n_in,
                              void* d_out, int out_size, void* d_ws, size_t ws_size,
                              hipStream_t stream) {
    const float* Q = (const float*)d_in[0];
    const float* K = (const float*)d_in[1];
    const float* V = (const float*)d_in[2];
    float* O = (float*)d_out;
    dim3 grid(256), block(256);
    hipLaunchKernelGGL(fmha_fwd, grid, block, 0, stream, Q, K, V, O);
}